// Round 18
// baseline (599.938 us; speedup 1.0000x reference)
//
#include <hip/hip_runtime.h>
#include <hip/hip_fp16.h>
#include <math.h>

#define BD 256
#define CAP 192
#define PBLK 2048

#define RED16(v) { v += __shfl_xor(v, 1, 64); v += __shfl_xor(v, 2, 64); \
                   v += __shfl_xor(v, 4, 64); v += __shfl_xor(v, 8, 64); }
#define REDQ(v)  { v += __shfl_xor(v, 16, 64); v += __shfl_xor(v, 32, 64); }

__device__ __forceinline__ __half2 shflxor_h2(__half2 v, int off) {
  int i = __shfl_xor(*(int*)&v, off, 64);
  return *(__half2*)&i;
}
#define REDQH(v)  { v = __hadd2(v, shflxor_h2(v, 16)); v = __hadd2(v, shflxor_h2(v, 32)); }
#define RED16H(v) { v = __hadd2(v, shflxor_h2(v, 1)); v = __hadd2(v, shflxor_h2(v, 2)); \
                    v = __hadd2(v, shflxor_h2(v, 4)); v = __hadd2(v, shflxor_h2(v, 8)); }

// ---------------- init: out = entity_emb (f32); emb16 = fp16(entity_emb); deg = 0 ----------------
__global__ void k_init(const float4* __restrict__ ent, uint2* __restrict__ e16,
                       float4* __restrict__ out, int n4, int* __restrict__ deg, int N) {
  int i = blockIdx.x * BD + threadIdx.x;
  if (i < n4) {
    float4 v = ent[i];
    out[i] = v;
    __half2 h01 = __floats2half2_rn(v.x, v.y);
    __half2 h23 = __floats2half2_rn(v.z, v.w);
    uint2 st; st.x = *(unsigned int*)&h01; st.y = *(unsigned int*)&h23;
    e16[i] = st;
  }
  if (i < N) deg[i] = 0;
}

// ---------------- CSR build ----------------
__global__ void k_deg(const int* __restrict__ head, int* __restrict__ deg, int E) {
  int e = blockIdx.x * BD + threadIdx.x;
  if (e < E) atomicAdd(&deg[head[e]], 1);
}

__global__ void k_scan_a(const int* __restrict__ deg, int* __restrict__ rowptr,
                         int* __restrict__ bsum, int N) {
  __shared__ int s[BD];
  int t = threadIdx.x, i = blockIdx.x * BD + t;
  int v = (i < N) ? deg[i] : 0;
  s[t] = v; __syncthreads();
  for (int off = 1; off < BD; off <<= 1) {
    int add = (t >= off) ? s[t - off] : 0;
    __syncthreads();
    s[t] += add;
    __syncthreads();
  }
  if (i < N) rowptr[i] = s[t] - v;
  if (t == BD - 1) bsum[blockIdx.x] = s[t];
}

__global__ void k_scan_b(const int* __restrict__ bsum, int* __restrict__ boff, int nb) {
  __shared__ int s[512];
  int t = threadIdx.x;
  int v = (t < nb) ? bsum[t] : 0;
  s[t] = v; __syncthreads();
  for (int off = 1; off < 512; off <<= 1) {
    int add = (t >= off) ? s[t - off] : 0;
    __syncthreads();
    s[t] += add;
    __syncthreads();
  }
  boff[t] = s[t] - v;
}

__global__ void k_scan_c(int* __restrict__ rowptr, int* __restrict__ cur,
                         const int* __restrict__ boff, int N, int E) {
  int i = blockIdx.x * BD + threadIdx.x;
  if (i < N) { int v = rowptr[i] + boff[blockIdx.x]; rowptr[i] = v; cur[i] = v; }
  if (i == 0) rowptr[N] = E;
}

// ---------------- scatter: epk[p] = tail*32 + rt; hpk[p] = head ----------------
__global__ void k_scatter(const int* __restrict__ head, const int* __restrict__ tail,
                          const int* __restrict__ etype, int* __restrict__ cur,
                          int* __restrict__ epk, int* __restrict__ hpk, int E) {
  int e = blockIdx.x * BD + threadIdx.x;
  if (e < E) {
    int h = head[e];
    int p = atomicAdd(&cur[h], 1);
    epk[p] = tail[e] * 32 + (etype[e] - 1);
    hpk[p] = h;
  }
}

// ---------------- M_h = Wq_h @ Wk_h^T : Mf[m][i*4+h]; also fills w16 mirror ----------------
__global__ void k_m(const float* __restrict__ Wq, const float* __restrict__ Wk,
                    const float* __restrict__ weight,
                    float* __restrict__ Mf, __half* __restrict__ w16) {
  int tid = blockIdx.x * BD + threadIdx.x;   // 0..16383
  int c = tid & 255;
  int m = tid >> 8;
  int i = c >> 2, h = c & 3;
  const float* wq = Wq + m * 64 + h * 16;
  const float* wk = Wk + i * 64 + h * 16;
  float acc = 0.f;
#pragma unroll
  for (int d = 0; d < 16; d++) acc = fmaf(wq[d], wk[d], acc);
  Mf[tid] = acc;
  if (tid < 2048) {
    int r = tid >> 6, j = tid & 63;
    w16[tid] = __float2half((r < 31) ? weight[r * 64 + j] : 0.f);
  }
}

// ---------------- G = emb16 @ Mf  -> fp16  (LDS-tiled, 64 nodes/block) ----------------
__global__ __launch_bounds__(256) void k_g(const __half* __restrict__ e16,
                                           const float* __restrict__ Mf,
                                           uint2* __restrict__ Gh2, int N) {
  __shared__ float lM[64 * 256];             // 64 KB
  int t = threadIdx.x;
  const float4* Mf4 = (const float4*)Mf;
  float4* lM4 = (float4*)lM;
  for (int i = t; i < 4096; i += BD) lM4[i] = Mf4[i];
  __syncthreads();
  int lane = t & 63, w = t >> 6;
  int nloc0 = blockIdx.x * 64 + w * 16;
#pragma unroll
  for (int b = 0; b < 2; b++) {
    int nl = nloc0 + b * 8;
    float4 acc[8];
#pragma unroll
    for (int ni = 0; ni < 8; ni++) acc[ni] = make_float4(0.f, 0.f, 0.f, 0.f);
#pragma unroll 4
    for (int m = 0; m < 64; m += 2) {
      float4 Mv0 = lM4[m * 64 + lane];
      float4 Mv1 = lM4[(m + 1) * 64 + lane];
#pragma unroll
      for (int ni = 0; ni < 8; ni++) {
        __half2 eh = *(const __half2*)(e16 + (size_t)(nl + ni) * 64 + m);  // over-read safe
        float2 ef = __half22float2(eh);
        acc[ni].x = fmaf(ef.x, Mv0.x, acc[ni].x);
        acc[ni].y = fmaf(ef.x, Mv0.y, acc[ni].y);
        acc[ni].z = fmaf(ef.x, Mv0.z, acc[ni].z);
        acc[ni].w = fmaf(ef.x, Mv0.w, acc[ni].w);
        acc[ni].x = fmaf(ef.y, Mv1.x, acc[ni].x);
        acc[ni].y = fmaf(ef.y, Mv1.y, acc[ni].y);
        acc[ni].z = fmaf(ef.y, Mv1.z, acc[ni].z);
        acc[ni].w = fmaf(ef.y, Mv1.w, acc[ni].w);
      }
    }
#pragma unroll
    for (int ni = 0; ni < 8; ni++)
      if (nl + ni < N) {
        __half2 h01 = __floats2half2_rn(acc[ni].x, acc[ni].y);
        __half2 h23 = __floats2half2_rn(acc[ni].z, acc[ni].w);
        uint2 st;
        st.x = *(unsigned int*)&h01;
        st.y = *(unsigned int*)&h23;
        Gh2[(size_t)(nl + ni) * 64 + lane] = st;
      }
  }
}

// ---------------- edge-parallel attention: xat[e] = 4 fp16 exps ----------------
__global__ __launch_bounds__(256) void k_att(const uint2* __restrict__ e16,
                        const uint2* __restrict__ w16, const uint4* __restrict__ Ghq,
                        const int* __restrict__ epk, const int* __restrict__ hpk,
                        uint2* __restrict__ xat, int E) {
  int t = threadIdx.x, lane = t & 63, w = t >> 6, q = lane >> 4, s = lane & 15;
  int wid = blockIdx.x * 4 + w, nw = gridDim.x * 4;
  int NG = (E + 3) >> 2;
  for (int g = wid; g < NG; g += nw) {
    int e = g * 4 + q;
    int ee = min(e, E - 1);
    int cmb = epk[ee];
    int hn  = hpk[ee];
    uint2 eu = e16[(size_t)(cmb >> 5) * 16 + s];
    uint2 ru = w16[((cmb & 31) << 4) + s];
    uint4 ga = Ghq[(size_t)hn * 32 + s * 2];
    uint4 gb = Ghq[(size_t)hn * 32 + s * 2 + 1];
    __half2 x01 = __hmul2(*(__half2*)&eu.x, *(__half2*)&ru.x);
    __half2 x23 = __hmul2(*(__half2*)&eu.y, *(__half2*)&ru.y);
    __half2 b0 = __low2half2(x01), b1 = __high2half2(x01);
    __half2 b2 = __low2half2(x23), b3 = __high2half2(x23);
    __half2 a01 = __hmul2(b0, *(__half2*)&ga.x);
    a01 = __hfma2(b1, *(__half2*)&ga.z, a01);
    a01 = __hfma2(b2, *(__half2*)&gb.x, a01);
    a01 = __hfma2(b3, *(__half2*)&gb.z, a01);
    __half2 a23 = __hmul2(b0, *(__half2*)&ga.y);
    a23 = __hfma2(b1, *(__half2*)&ga.w, a23);
    a23 = __hfma2(b2, *(__half2*)&gb.y, a23);
    a23 = __hfma2(b3, *(__half2*)&gb.w, a23);
    RED16H(a01) RED16H(a23)
    float2 fa01 = __half22float2(a01);
    float2 fa23 = __half22float2(a23);
    fa01.x = fminf(10.f, fmaxf(-10.f, fa01.x));
    fa01.y = fminf(10.f, fmaxf(-10.f, fa01.y));
    fa23.x = fminf(10.f, fmaxf(-10.f, fa23.x));
    fa23.y = fminf(10.f, fmaxf(-10.f, fa23.y));
    if (s == 0 && e < E) {
      __half2 p01 = __floats2half2_rn(__expf(fa01.x), __expf(fa01.y));
      __half2 p23 = __floats2half2_rn(__expf(fa23.x), __expf(fa23.y));
      xat[e] = make_uint2(*(unsigned int*)&p01, *(unsigned int*)&p23);
    }
  }
}

// ---------------- node pass: den + S + S@Wv -> kg16  (persistent, no butterfly) ----------------
__global__ __launch_bounds__(256) void k_s(const uint2* __restrict__ e16,
                        const uint2* __restrict__ w16, const uint2* __restrict__ xat,
                        const float* __restrict__ Wv,
                        const int* __restrict__ epk, const int* __restrict__ rowptr,
                        __half* __restrict__ kg16, int N) {
  __shared__ float SL[4 * 272];
  int t = threadIdx.x, lane = t & 63, w = t >> 6, q = lane >> 4, s = lane & 15;
  float* L = SL + w * 272;
  int wid = blockIdx.x * 4 + w, nw = gridDim.x * 4;
  const __half2 z2 = __float2half2_rn(0.f);
  for (int n = wid; n < N; n += nw) {
    int base = rowptr[n], deg = rowptr[n + 1] - base;
    float4 den = make_float4(0.f, 0.f, 0.f, 0.f);
    __half2 S0a = z2, S0b = z2, S1a = z2, S1b = z2;
    __half2 S2a = z2, S2b = z2, S3a = z2, S3b = z2;
    for (int g0 = 0; g0 < deg; g0 += 4) {
      int k = g0 + q;
      bool valid = (k < deg);
      int kk = min(k, deg - 1);
      int cmb = epk[base + kk];
      uint2 ea = xat[base + kk];
      uint2 eu = e16[(size_t)(cmb >> 5) * 16 + s];
      uint2 ru = w16[((cmb & 31) << 4) + s];
      __half2 x01 = __hmul2(*(__half2*)&eu.x, *(__half2*)&ru.x);
      __half2 x23 = __hmul2(*(__half2*)&eu.y, *(__half2*)&ru.y);
      __half2 b0 = __low2half2(x01), b1 = __high2half2(x01);
      __half2 b2 = __low2half2(x23), b3 = __high2half2(x23);
      __half2 e01 = valid ? *(__half2*)&ea.x : z2;
      __half2 e23 = valid ? *(__half2*)&ea.y : z2;
      float2 f0 = __half22float2(e01);
      float2 f1 = __half22float2(e23);
      den.x += f0.x; den.y += f0.y; den.z += f1.x; den.w += f1.y;
      S0a = __hfma2(e01, b0, S0a); S0b = __hfma2(e23, b0, S0b);
      S1a = __hfma2(e01, b1, S1a); S1b = __hfma2(e23, b1, S1b);
      S2a = __hfma2(e01, b2, S2a); S2b = __hfma2(e23, b2, S2b);
      S3a = __hfma2(e01, b3, S3a); S3b = __hfma2(e23, b3, S3b);
    }
    REDQ(den.x) REDQ(den.y) REDQ(den.z) REDQ(den.w)
    REDQH(S0a) REDQH(S0b) REDQH(S1a) REDQH(S1b)
    REDQH(S2a) REDQH(S2b) REDQH(S3a) REDQH(S3b)
    float4 inv;
    inv.x = 1.f / (den.x + 1e-8f); inv.y = 1.f / (den.y + 1e-8f);
    inv.z = 1.f / (den.z + 1e-8f); inv.w = 1.f / (den.w + 1e-8f);
    float2 c0, c1;
    c0 = __half22float2(S0a); c1 = __half22float2(S0b);
    float s0h0 = c0.x * inv.x, s0h1 = c0.y * inv.y, s0h2 = c1.x * inv.z, s0h3 = c1.y * inv.w;
    c0 = __half22float2(S1a); c1 = __half22float2(S1b);
    float s1h0 = c0.x * inv.x, s1h1 = c0.y * inv.y, s1h2 = c1.x * inv.z, s1h3 = c1.y * inv.w;
    c0 = __half22float2(S2a); c1 = __half22float2(S2b);
    float s2h0 = c0.x * inv.x, s2h1 = c0.y * inv.y, s2h2 = c1.x * inv.z, s2h3 = c1.y * inv.w;
    c0 = __half22float2(S3a); c1 = __half22float2(S3b);
    float s3h0 = c0.x * inv.x, s3h1 = c0.y * inv.y, s3h2 = c1.x * inv.z, s3h3 = c1.y * inv.w;
    if (q == 0) {
      *(float4*)(L +       s * 4) = make_float4(s0h0, s1h0, s2h0, s3h0);
      *(float4*)(L +  68 + s * 4) = make_float4(s0h1, s1h1, s2h1, s3h1);
      *(float4*)(L + 136 + s * 4) = make_float4(s0h2, s1h2, s2h2, s3h2);
      *(float4*)(L + 204 + s * 4) = make_float4(s0h3, s1h3, s2h3, s3h3);
    }
    const float4* L4 = (const float4*)(L + q * 68);
    float acc = 0.f;
#pragma unroll
    for (int i4 = 0; i4 < 16; i4++) {
      float4 Lv = L4[i4];
      acc = fmaf(Lv.x, Wv[(i4 * 4 + 0) * 64 + lane], acc);
      acc = fmaf(Lv.y, Wv[(i4 * 4 + 1) * 64 + lane], acc);
      acc = fmaf(Lv.z, Wv[(i4 * 4 + 2) * 64 + lane], acc);
      acc = fmaf(Lv.w, Wv[(i4 * 4 + 3) * 64 + lane], acc);
    }
    kg16[(size_t)n * 64 + lane] = __float2half(acc);
  }
}

// ---------------- D = KG^2 @ REL^2T  (64 nodes/block, LDS-staged, fp16 kg) ----------------
__global__ __launch_bounds__(256) void k_d(const uint4* __restrict__ kg16q,
                    const float* __restrict__ weight,
                    float* __restrict__ D, int N) {
  __shared__ float R2T[64 * 32];       // [j][r] = weight[r][j]^2
  __shared__ float KG2[64 * 68];       // [node][j] padded (squares)
  int t = threadIdx.x;
  for (int i = t; i < 2048; i += BD) {
    int j = i >> 5, r = i & 31;
    float v = (r < 31) ? weight[r * 64 + j] : 0.f;
    R2T[i] = v * v;
  }
  int nbase = blockIdx.x * 64;
  const uint4* src = kg16q + (size_t)nbase * 8;   // 8 uint4 (64 halves) per node
  for (int i = t; i < 512; i += BD) {
    uint4 v = src[i];                  // over-read past N stays in ws: safe
    float* dst = KG2 + (i >> 3) * 68 + (i & 7) * 8;
    float2 f;
    f = __half22float2(*(__half2*)&v.x); dst[0] = f.x * f.x; dst[1] = f.y * f.y;
    f = __half22float2(*(__half2*)&v.y); dst[2] = f.x * f.x; dst[3] = f.y * f.y;
    f = __half22float2(*(__half2*)&v.z); dst[4] = f.x * f.x; dst[5] = f.y * f.y;
    f = __half22float2(*(__half2*)&v.w); dst[6] = f.x * f.x; dst[7] = f.y * f.y;
  }
  __syncthreads();
  int r = t & 31, ng = t >> 5;
  float acc[8] = {0.f, 0.f, 0.f, 0.f, 0.f, 0.f, 0.f, 0.f};
  const float* kbase = KG2 + ng * 8 * 68;
#pragma unroll 4
  for (int j4 = 0; j4 < 16; j4++) {
    float r0 = R2T[(j4 * 4 + 0) * 32 + r];
    float r1 = R2T[(j4 * 4 + 1) * 32 + r];
    float r2 = R2T[(j4 * 4 + 2) * 32 + r];
    float r3 = R2T[(j4 * 4 + 3) * 32 + r];
#pragma unroll
    for (int ni = 0; ni < 8; ni++) {
      const float* kv = kbase + ni * 68 + j4 * 4;
      acc[ni] = fmaf(kv[3], r3, fmaf(kv[2], r2, fmaf(kv[1], r1, fmaf(kv[0], r0, acc[ni]))));
    }
  }
  if (r < 31) {
    int nlim = N - nbase;
#pragma unroll
    for (int ni = 0; ni < 8; ni++) {
      int nl = ng * 8 + ni;
      if (nl < nlim) D[(size_t)(nbase + nl) * 32 + r] = acc[ni];
    }
  }
}

// ---- scatter-softmax: pass1 exp->LDS + sum (parallel); pass2 lean agg ----
__global__ __launch_bounds__(256) void k_aggnorm(const uint2* __restrict__ e16,
                          const float* __restrict__ D,
                          const int* __restrict__ epk, const int* __restrict__ rowptr,
                          uint2* __restrict__ en16, float* __restrict__ out, int N) {
  __shared__ float wls[4 * CAP];
  __shared__ float DnL[4 * 32];
  int t = threadIdx.x, lane = t & 63, w = t >> 6, q = lane >> 4, s = lane & 15;
  float* wl = wls + w * CAP;
  float* Dn = DnL + w * 32;
  int wid = blockIdx.x * 4 + w, nw = gridDim.x * 4;
  for (int n = wid; n < N; n += nw) {
    int base = rowptr[n], deg = rowptr[n + 1] - base;
    if (lane < 32) Dn[lane] = (lane < 31) ? D[(size_t)n * 32 + lane] : 0.f;
    float4 agg = make_float4(0.f, 0.f, 0.f, 0.f);
    float sacc = 0.f;
    for (int k = lane; k < deg; k += 64) {
      int cmb = epk[base + k];
      float a = __expf(Dn[cmb & 31] * D[cmb]);   // shift-free: w tiny, >=0
      if (k < CAP) wl[k] = a;
      sacc += a;
    }
    RED16(sacc) REDQ(sacc)
    for (int g0 = 0; g0 < deg; g0 += 4) {
      int k = g0 + q;
      bool valid = (k < deg);
      int kk = min(k, deg - 1);
      int cmb = epk[base + kk];
      float a = valid ? ((kk < CAP) ? wl[kk]
                                    : __expf(Dn[cmb & 31] * D[cmb])) : 0.f;
      uint2 eu = e16[(size_t)(cmb >> 5) * 16 + s];
      float2 ef0 = __half22float2(*(__half2*)&eu.x);
      float2 ef1 = __half22float2(*(__half2*)&eu.y);
      agg.x = fmaf(a, ef0.x, agg.x);
      agg.y = fmaf(a, ef0.y, agg.y);
      agg.z = fmaf(a, ef1.x, agg.z);
      agg.w = fmaf(a, ef1.y, agg.w);
    }
    REDQ(agg.x) REDQ(agg.y) REDQ(agg.z) REDQ(agg.w)
    float sinv = 1.f / (sacc + 1e-16f);
    agg.x *= sinv; agg.y *= sinv; agg.z *= sinv; agg.w *= sinv;
    float ss = agg.x * agg.x + agg.y * agg.y + agg.z * agg.z + agg.w * agg.w;
    RED16(ss)
    float nr = fmaxf(sqrtf(ss), 1e-12f);
    float rin = 1.f / nr;
    float4 en;
    en.x = agg.x * rin; en.y = agg.y * rin; en.z = agg.z * rin; en.w = agg.w * rin;
    if (q == 0) {
      __half2 h01 = __floats2half2_rn(en.x, en.y);
      __half2 h23 = __floats2half2_rn(en.z, en.w);
      uint2 st; st.x = *(unsigned int*)&h01; st.y = *(unsigned int*)&h23;
      en16[(size_t)n * 16 + s] = st;
      float4* oo = (float4*)(out + (size_t)n * 64) + s;
      float4 ov = *oo;
      ov.x += en.x; ov.y += en.y; ov.z += en.z; ov.w += en.w;
      *oo = ov;
    }
  }
}

extern "C" void kernel_launch(void* const* d_in, const int* in_sizes, int n_in,
                              void* d_out, int out_size, void* d_ws, size_t ws_size,
                              hipStream_t stream) {
  const float* ent    = (const float*)d_in[0];
  const float* weight = (const float*)d_in[1];
  const float* Wq     = (const float*)d_in[2];
  const float* Wk     = (const float*)d_in[3];
  const float* Wv     = (const float*)d_in[4];
  const int*   eidx   = (const int*)d_in[5];
  const int*   etype  = (const int*)d_in[6];
  int N = in_sizes[0] / 64;
  int E = in_sizes[6];
  const int* head = eidx;
  const int* tail = eidx + E;

  // workspace layout (float units) -- ~97 MB
  float* ws    = (float*)d_ws;
  size_t o = 0;
  float* e16A  = ws + o; o += (size_t)N * 32;     // fp16 emb (N*64 halves)
  float* e16B  = ws + o; o += (size_t)N * 32;
  float* kg16  = ws + o; o += (size_t)N * 16;     // fp16 kg (N*64 halves)
  float* Gbuf  = ws + o; o += (size_t)N * 128;    // fp16 G; reused as D (N*32 f32)
  float* Mf    = ws + o; o += 64 * 256;
  float* w16   = ws + o; o += 1024;               // fp16 weight
  int* epk     = (int*)(ws + o); o += (size_t)E;
  int* hpk     = (int*)(ws + o); o += (size_t)E;
  float* xat   = ws + o; o += (size_t)E * 2;      // 4 fp16 exps per edge
  int* rowptr  = (int*)(ws + o); o += N + 1;
  int* deg     = (int*)(ws + o); o += N;
  int* cur     = (int*)(ws + o); o += N;
  int* bsum    = (int*)(ws + o); o += 512;
  int* boff    = (int*)(ws + o); o += 512;
  float* Dbuf  = Gbuf;

  int n4  = N * 64 / 4;
  int bl4 = (n4 + BD - 1) / BD;
  int ebl = (E + BD - 1) / BD;
  int sbl = (N + BD - 1) / BD;

  k_init<<<bl4, BD, 0, stream>>>((const float4*)ent, (uint2*)e16A, (float4*)d_out,
                                 n4, deg, N);
  k_deg    <<<ebl, BD, 0, stream>>>(head, deg, E);
  k_scan_a <<<sbl, BD, 0, stream>>>(deg, rowptr, bsum, N);
  k_scan_b <<<1, 512, 0, stream>>>(bsum, boff, sbl);
  k_scan_c <<<sbl, BD, 0, stream>>>(rowptr, cur, boff, N, E);
  k_scatter<<<ebl, BD, 0, stream>>>(head, tail, etype, cur, epk, hpk, E);

  float* emb = e16A;
  float* alt = e16B;
  for (int l = 0; l < 2; l++) {
    const float* wq = Wq + (size_t)l * 64 * 64;
    const float* wk = Wk + (size_t)l * 64 * 64;
    const float* wv = Wv + (size_t)l * 64 * 64;

    k_m<<<64, BD, 0, stream>>>(wq, wk, weight, Mf, (__half*)w16);
    k_g<<<(N + 63) / 64, BD, 0, stream>>>((const __half*)emb, Mf, (uint2*)Gbuf, N);
    k_att<<<PBLK, BD, 0, stream>>>((const uint2*)emb, (const uint2*)w16,
                                   (const uint4*)Gbuf, epk, hpk, (uint2*)xat, E);
    k_s<<<PBLK, BD, 0, stream>>>((const uint2*)emb, (const uint2*)w16,
                                 (const uint2*)xat, wv, epk, rowptr,
                                 (__half*)kg16, N);
    k_d<<<(N + 63) / 64, BD, 0, stream>>>((const uint4*)kg16, weight, Dbuf, N);
    k_aggnorm<<<PBLK, BD, 0, stream>>>((const uint2*)emb, Dbuf, epk, rowptr,
                                       (uint2*)alt, (float*)d_out, N);
    float* tmp = emb; emb = alt; alt = tmp;
  }
}

// Round 19
// 557.399 us; speedup vs baseline: 1.0763x; 1.0763x over previous
//
#include <hip/hip_runtime.h>
#include <hip/hip_fp16.h>
#include <math.h>

#define BD 256
#define CAP 192
#define PBLK 2048

#define RED16(v) { v += __shfl_xor(v, 1, 64); v += __shfl_xor(v, 2, 64); \
                   v += __shfl_xor(v, 4, 64); v += __shfl_xor(v, 8, 64); }
#define REDQ(v)  { v += __shfl_xor(v, 16, 64); v += __shfl_xor(v, 32, 64); }

__device__ __forceinline__ __half2 shflxor_h2(__half2 v, int off) {
  int i = __shfl_xor(*(int*)&v, off, 64);
  return *(__half2*)&i;
}
#define REDQH(v)  { v = __hadd2(v, shflxor_h2(v, 16)); v = __hadd2(v, shflxor_h2(v, 32)); }
#define RED16H(v) { v = __hadd2(v, shflxor_h2(v, 1)); v = __hadd2(v, shflxor_h2(v, 2)); \
                    v = __hadd2(v, shflxor_h2(v, 4)); v = __hadd2(v, shflxor_h2(v, 8)); }

// ---------------- init: out = entity_emb (f32); emb16 = fp16(entity_emb); deg = 0 ----------------
__global__ void k_init(const float4* __restrict__ ent, uint2* __restrict__ e16,
                       float4* __restrict__ out, int n4, int* __restrict__ deg, int N) {
  int i = blockIdx.x * BD + threadIdx.x;
  if (i < n4) {
    float4 v = ent[i];
    out[i] = v;
    __half2 h01 = __floats2half2_rn(v.x, v.y);
    __half2 h23 = __floats2half2_rn(v.z, v.w);
    uint2 st; st.x = *(unsigned int*)&h01; st.y = *(unsigned int*)&h23;
    e16[i] = st;
  }
  if (i < N) deg[i] = 0;
}

// ---------------- CSR build ----------------
__global__ void k_deg(const int* __restrict__ head, int* __restrict__ deg, int E) {
  int e = blockIdx.x * BD + threadIdx.x;
  if (e < E) atomicAdd(&deg[head[e]], 1);
}

__global__ void k_scan_a(const int* __restrict__ deg, int* __restrict__ rowptr,
                         int* __restrict__ bsum, int N) {
  __shared__ int s[BD];
  int t = threadIdx.x, i = blockIdx.x * BD + t;
  int v = (i < N) ? deg[i] : 0;
  s[t] = v; __syncthreads();
  for (int off = 1; off < BD; off <<= 1) {
    int add = (t >= off) ? s[t - off] : 0;
    __syncthreads();
    s[t] += add;
    __syncthreads();
  }
  if (i < N) rowptr[i] = s[t] - v;
  if (t == BD - 1) bsum[blockIdx.x] = s[t];
}

__global__ void k_scan_b(const int* __restrict__ bsum, int* __restrict__ boff, int nb) {
  __shared__ int s[512];
  int t = threadIdx.x;
  int v = (t < nb) ? bsum[t] : 0;
  s[t] = v; __syncthreads();
  for (int off = 1; off < 512; off <<= 1) {
    int add = (t >= off) ? s[t - off] : 0;
    __syncthreads();
    s[t] += add;
    __syncthreads();
  }
  boff[t] = s[t] - v;
}

__global__ void k_scan_c(int* __restrict__ rowptr, int* __restrict__ cur,
                         const int* __restrict__ boff, int N, int E) {
  int i = blockIdx.x * BD + threadIdx.x;
  if (i < N) { int v = rowptr[i] + boff[blockIdx.x]; rowptr[i] = v; cur[i] = v; }
  if (i == 0) rowptr[N] = E;
}

// ---------------- scatter: epk[p] = tail*32 + rt  (D index directly) ----------------
__global__ void k_scatter(const int* __restrict__ head, const int* __restrict__ tail,
                          const int* __restrict__ etype,
                          int* __restrict__ cur, int* __restrict__ epk, int E) {
  int e = blockIdx.x * BD + threadIdx.x;
  if (e < E) {
    int p = atomicAdd(&cur[head[e]], 1);
    epk[p] = tail[e] * 32 + (etype[e] - 1);
  }
}

// ---------------- M_h = Wq_h @ Wk_h^T : Mf[m][i*4+h]; also fills w16 mirror ----------------
__global__ void k_m(const float* __restrict__ Wq, const float* __restrict__ Wk,
                    const float* __restrict__ weight,
                    float* __restrict__ Mf, __half* __restrict__ w16) {
  int tid = blockIdx.x * BD + threadIdx.x;   // 0..16383
  int c = tid & 255;
  int m = tid >> 8;
  int i = c >> 2, h = c & 3;
  const float* wq = Wq + m * 64 + h * 16;
  const float* wk = Wk + i * 64 + h * 16;
  float acc = 0.f;
#pragma unroll
  for (int d = 0; d < 16; d++) acc = fmaf(wq[d], wk[d], acc);
  Mf[tid] = acc;
  if (tid < 2048) {
    int r = tid >> 6, j = tid & 63;
    w16[tid] = __float2half((r < 31) ? weight[r * 64 + j] : 0.f);
  }
}

// ---------------- G = emb16 @ Mf  -> fp16  (LDS-tiled, 64 nodes/block) ----------------
__global__ __launch_bounds__(256) void k_g(const __half* __restrict__ e16,
                                           const float* __restrict__ Mf,
                                           uint2* __restrict__ Gh2, int N) {
  __shared__ float lM[64 * 256];             // 64 KB
  int t = threadIdx.x;
  const float4* Mf4 = (const float4*)Mf;
  float4* lM4 = (float4*)lM;
  for (int i = t; i < 4096; i += BD) lM4[i] = Mf4[i];
  __syncthreads();
  int lane = t & 63, w = t >> 6;
  int nloc0 = blockIdx.x * 64 + w * 16;
#pragma unroll
  for (int b = 0; b < 2; b++) {
    int nl = nloc0 + b * 8;
    float4 acc[8];
#pragma unroll
    for (int ni = 0; ni < 8; ni++) acc[ni] = make_float4(0.f, 0.f, 0.f, 0.f);
#pragma unroll 4
    for (int m = 0; m < 64; m += 2) {
      float4 Mv0 = lM4[m * 64 + lane];
      float4 Mv1 = lM4[(m + 1) * 64 + lane];
#pragma unroll
      for (int ni = 0; ni < 8; ni++) {
        __half2 eh = *(const __half2*)(e16 + (size_t)(nl + ni) * 64 + m);  // over-read safe
        float2 ef = __half22float2(eh);
        acc[ni].x = fmaf(ef.x, Mv0.x, acc[ni].x);
        acc[ni].y = fmaf(ef.x, Mv0.y, acc[ni].y);
        acc[ni].z = fmaf(ef.x, Mv0.z, acc[ni].z);
        acc[ni].w = fmaf(ef.x, Mv0.w, acc[ni].w);
        acc[ni].x = fmaf(ef.y, Mv1.x, acc[ni].x);
        acc[ni].y = fmaf(ef.y, Mv1.y, acc[ni].y);
        acc[ni].z = fmaf(ef.y, Mv1.z, acc[ni].z);
        acc[ni].w = fmaf(ef.y, Mv1.w, acc[ni].w);
      }
    }
#pragma unroll
    for (int ni = 0; ni < 8; ni++)
      if (nl + ni < N) {
        __half2 h01 = __floats2half2_rn(acc[ni].x, acc[ni].y);
        __half2 h23 = __floats2half2_rn(acc[ni].z, acc[ni].w);
        uint2 st;
        st.x = *(unsigned int*)&h01;
        st.y = *(unsigned int*)&h23;
        Gh2[(size_t)(nl + ni) * 64 + lane] = st;
      }
  }
}

// ---------------- fused: att + softmax-den + S + S@Wv -> kg (persistent, idx-prefetch) ----------------
__global__ __launch_bounds__(256) void k_fused(const uint2* __restrict__ e16,
                        const uint2* __restrict__ w16,
                        const uint4* __restrict__ Ghq, const float* __restrict__ Wv,
                        const int* __restrict__ epk, const int* __restrict__ rowptr,
                        float* __restrict__ kg, int N) {
  __shared__ float SL[4 * 272];              // per-wave 4 segments of 68 (bank-skewed)
  int t = threadIdx.x, lane = t & 63, w = t >> 6, q = lane >> 4, s = lane & 15;
  float* L = SL + w * 272;
  int wid = blockIdx.x * 4 + w, nw = gridDim.x * 4;
  const __half2 z2 = __float2half2_rn(0.f);
  for (int n = wid; n < N; n += nw) {
    uint4 ga = Ghq[(size_t)n * 32 + s * 2];
    uint4 gb = Ghq[(size_t)n * 32 + s * 2 + 1];
    __half2 c0h01 = *(__half2*)&ga.x, c0h23 = *(__half2*)&ga.y;
    __half2 c1h01 = *(__half2*)&ga.z, c1h23 = *(__half2*)&ga.w;
    __half2 c2h01 = *(__half2*)&gb.x, c2h23 = *(__half2*)&gb.y;
    __half2 c3h01 = *(__half2*)&gb.z, c3h23 = *(__half2*)&gb.w;

    int base = rowptr[n], deg = rowptr[n + 1] - base;
    float4 den = make_float4(0.f, 0.f, 0.f, 0.f);
    __half2 S0a = z2, S0b = z2, S1a = z2, S1b = z2;
    __half2 S2a = z2, S2b = z2, S3a = z2, S3b = z2;
    int cmb = (deg > 0) ? epk[base + min(q, deg - 1)] : 0;
    for (int g0 = 0; g0 < deg; g0 += 4) {
      int k = g0 + q;
      bool valid = (k < deg);
      // prefetch next group's index (wave-uniform branch)
      int cmbn = cmb;
      if (g0 + 4 < deg) cmbn = epk[base + min(g0 + 4 + q, deg - 1)];
      uint2 eu = e16[(size_t)(cmb >> 5) * 16 + s];
      uint2 ru = w16[((cmb & 31) << 4) + s];
      __half2 x01 = __hmul2(*(__half2*)&eu.x, *(__half2*)&ru.x);
      __half2 x23 = __hmul2(*(__half2*)&eu.y, *(__half2*)&ru.y);
      __half2 b0 = __low2half2(x01), b1 = __high2half2(x01);
      __half2 b2 = __low2half2(x23), b3 = __high2half2(x23);
      __half2 a01 = __hmul2(b0, c0h01);
      a01 = __hfma2(b1, c1h01, a01);
      a01 = __hfma2(b2, c2h01, a01);
      a01 = __hfma2(b3, c3h01, a01);
      __half2 a23 = __hmul2(b0, c0h23);
      a23 = __hfma2(b1, c1h23, a23);
      a23 = __hfma2(b2, c2h23, a23);
      a23 = __hfma2(b3, c3h23, a23);
      RED16H(a01) RED16H(a23)
      float2 fa01 = __half22float2(a01);
      float2 fa23 = __half22float2(a23);
      fa01.x = fminf(10.f, fmaxf(-10.f, fa01.x));
      fa01.y = fminf(10.f, fmaxf(-10.f, fa01.y));
      fa23.x = fminf(10.f, fmaxf(-10.f, fa23.x));
      fa23.y = fminf(10.f, fmaxf(-10.f, fa23.y));
      float4 ev;
      ev.x = valid ? __expf(fa01.x) : 0.f;
      ev.y = valid ? __expf(fa01.y) : 0.f;
      ev.z = valid ? __expf(fa23.x) : 0.f;
      ev.w = valid ? __expf(fa23.y) : 0.f;
      den.x += ev.x; den.y += ev.y; den.z += ev.z; den.w += ev.w;
      __half2 e01 = __floats2half2_rn(ev.x, ev.y);
      __half2 e23 = __floats2half2_rn(ev.z, ev.w);
      S0a = __hfma2(e01, b0, S0a); S0b = __hfma2(e23, b0, S0b);
      S1a = __hfma2(e01, b1, S1a); S1b = __hfma2(e23, b1, S1b);
      S2a = __hfma2(e01, b2, S2a); S2b = __hfma2(e23, b2, S2b);
      S3a = __hfma2(e01, b3, S3a); S3b = __hfma2(e23, b3, S3b);
      cmb = cmbn;
    }
    REDQ(den.x) REDQ(den.y) REDQ(den.z) REDQ(den.w)
    REDQH(S0a) REDQH(S0b) REDQH(S1a) REDQH(S1b)
    REDQH(S2a) REDQH(S2b) REDQH(S3a) REDQH(S3b)
    float4 inv;
    inv.x = 1.f / (den.x + 1e-8f); inv.y = 1.f / (den.y + 1e-8f);
    inv.z = 1.f / (den.z + 1e-8f); inv.w = 1.f / (den.w + 1e-8f);
    float2 c0, c1;
    c0 = __half22float2(S0a); c1 = __half22float2(S0b);
    float s0h0 = c0.x * inv.x, s0h1 = c0.y * inv.y, s0h2 = c1.x * inv.z, s0h3 = c1.y * inv.w;
    c0 = __half22float2(S1a); c1 = __half22float2(S1b);
    float s1h0 = c0.x * inv.x, s1h1 = c0.y * inv.y, s1h2 = c1.x * inv.z, s1h3 = c1.y * inv.w;
    c0 = __half22float2(S2a); c1 = __half22float2(S2b);
    float s2h0 = c0.x * inv.x, s2h1 = c0.y * inv.y, s2h2 = c1.x * inv.z, s2h3 = c1.y * inv.w;
    c0 = __half22float2(S3a); c1 = __half22float2(S3b);
    float s3h0 = c0.x * inv.x, s3h1 = c0.y * inv.y, s3h2 = c1.x * inv.z, s3h3 = c1.y * inv.w;
    if (q == 0) {
      *(float4*)(L +       s * 4) = make_float4(s0h0, s1h0, s2h0, s3h0);
      *(float4*)(L +  68 + s * 4) = make_float4(s0h1, s1h1, s2h1, s3h1);
      *(float4*)(L + 136 + s * 4) = make_float4(s0h2, s1h2, s2h2, s3h2);
      *(float4*)(L + 204 + s * 4) = make_float4(s0h3, s1h3, s2h3, s3h3);
    }
    const float4* L4 = (const float4*)(L + q * 68);
    float acc = 0.f;
#pragma unroll
    for (int i4 = 0; i4 < 16; i4++) {
      float4 Lv = L4[i4];
      acc = fmaf(Lv.x, Wv[(i4 * 4 + 0) * 64 + lane], acc);
      acc = fmaf(Lv.y, Wv[(i4 * 4 + 1) * 64 + lane], acc);
      acc = fmaf(Lv.z, Wv[(i4 * 4 + 2) * 64 + lane], acc);
      acc = fmaf(Lv.w, Wv[(i4 * 4 + 3) * 64 + lane], acc);
    }
    kg[(size_t)n * 64 + lane] = acc;
  }
}

// ---------------- D = KG^2 @ REL^2T  (64 nodes/block, LDS-staged) ----------------
__global__ __launch_bounds__(256) void k_d(const float4* __restrict__ kg4,
                    const float* __restrict__ weight,
                    float* __restrict__ D, int N) {
  __shared__ float R2T[64 * 32];       // [j][r] = weight[r][j]^2
  __shared__ float KG2[64 * 68];       // [node][j] padded
  int t = threadIdx.x;
  for (int i = t; i < 2048; i += BD) {
    int j = i >> 5, r = i & 31;
    float v = (r < 31) ? weight[r * 64 + j] : 0.f;
    R2T[i] = v * v;
  }
  int nbase = blockIdx.x * 64;
  const float4* src = kg4 + (size_t)nbase * 16;
#pragma unroll
  for (int i = 0; i < 4; i++) {
    int idx = t + i * 256;
    float4 v = src[idx];               // may over-read past N into adjacent ws: safe
    float* dst = KG2 + (idx >> 4) * 68 + (idx & 15) * 4;
    dst[0] = v.x * v.x; dst[1] = v.y * v.y; dst[2] = v.z * v.z; dst[3] = v.w * v.w;
  }
  __syncthreads();
  int r = t & 31, ng = t >> 5;
  float acc[8] = {0.f, 0.f, 0.f, 0.f, 0.f, 0.f, 0.f, 0.f};
  const float* kbase = KG2 + ng * 8 * 68;
#pragma unroll 4
  for (int j4 = 0; j4 < 16; j4++) {
    float r0 = R2T[(j4 * 4 + 0) * 32 + r];
    float r1 = R2T[(j4 * 4 + 1) * 32 + r];
    float r2 = R2T[(j4 * 4 + 2) * 32 + r];
    float r3 = R2T[(j4 * 4 + 3) * 32 + r];
#pragma unroll
    for (int ni = 0; ni < 8; ni++) {
      float4 kv = *(const float4*)(kbase + ni * 68 + j4 * 4);
      acc[ni] = fmaf(kv.w, r3, fmaf(kv.z, r2, fmaf(kv.y, r1, fmaf(kv.x, r0, acc[ni]))));
    }
  }
  if (r < 31) {
    int nlim = N - nbase;
#pragma unroll
    for (int ni = 0; ni < 8; ni++) {
      int nl = ng * 8 + ni;
      if (nl < nlim) D[(size_t)(nbase + nl) * 32 + r] = acc[ni];
    }
  }
}

// ---- scatter-softmax: pass1 exp->LDS + sum (parallel); pass2 lean agg (idx-prefetch) ----
__global__ __launch_bounds__(256) void k_aggnorm(const uint2* __restrict__ e16,
                          const float* __restrict__ D,
                          const int* __restrict__ epk, const int* __restrict__ rowptr,
                          uint2* __restrict__ en16, float* __restrict__ out, int N) {
  __shared__ float wls[4 * CAP];
  __shared__ float DnL[4 * 32];
  int t = threadIdx.x, lane = t & 63, w = t >> 6, q = lane >> 4, s = lane & 15;
  float* wl = wls + w * CAP;
  float* Dn = DnL + w * 32;
  int wid = blockIdx.x * 4 + w, nw = gridDim.x * 4;
  for (int n = wid; n < N; n += nw) {
    int base = rowptr[n], deg = rowptr[n + 1] - base;
    if (lane < 32) Dn[lane] = (lane < 31) ? D[(size_t)n * 32 + lane] : 0.f;
    float4 agg = make_float4(0.f, 0.f, 0.f, 0.f);
    float sacc = 0.f;
    // pass 1: lane-parallel gather + exp + sum; cache exp in LDS
    for (int k = lane; k < deg; k += 64) {
      int cmb = epk[base + k];
      float a = __expf(Dn[cmb & 31] * D[cmb]);   // shift-free: w tiny, >=0
      if (k < CAP) wl[k] = a;
      sacc += a;
    }
    RED16(sacc) REDQ(sacc)
    // pass 2: quarter-parallel aggregation (exp from LDS cache, idx-prefetched)
    int cmb = (deg > 0) ? epk[base + min(q, deg - 1)] : 0;
    for (int g0 = 0; g0 < deg; g0 += 4) {
      int k = g0 + q;
      bool valid = (k < deg);
      int kk = min(k, deg - 1);
      int cmbn = cmb;
      if (g0 + 4 < deg) cmbn = epk[base + min(g0 + 4 + q, deg - 1)];
      float a = valid ? ((kk < CAP) ? wl[kk]
                                    : __expf(Dn[cmb & 31] * D[cmb])) : 0.f;
      uint2 eu = e16[(size_t)(cmb >> 5) * 16 + s];
      float2 ef0 = __half22float2(*(__half2*)&eu.x);
      float2 ef1 = __half22float2(*(__half2*)&eu.y);
      agg.x = fmaf(a, ef0.x, agg.x);
      agg.y = fmaf(a, ef0.y, agg.y);
      agg.z = fmaf(a, ef1.x, agg.z);
      agg.w = fmaf(a, ef1.y, agg.w);
      cmb = cmbn;
    }
    REDQ(agg.x) REDQ(agg.y) REDQ(agg.z) REDQ(agg.w)
    float sinv = 1.f / (sacc + 1e-16f);
    agg.x *= sinv; agg.y *= sinv; agg.z *= sinv; agg.w *= sinv;
    float ss = agg.x * agg.x + agg.y * agg.y + agg.z * agg.z + agg.w * agg.w;
    RED16(ss)
    float nr = fmaxf(sqrtf(ss), 1e-12f);
    float rin = 1.f / nr;
    float4 en;
    en.x = agg.x * rin; en.y = agg.y * rin; en.z = agg.z * rin; en.w = agg.w * rin;
    if (q == 0) {
      __half2 h01 = __floats2half2_rn(en.x, en.y);
      __half2 h23 = __floats2half2_rn(en.z, en.w);
      uint2 st; st.x = *(unsigned int*)&h01; st.y = *(unsigned int*)&h23;
      en16[(size_t)n * 16 + s] = st;
      float4* oo = (float4*)(out + (size_t)n * 64) + s;
      float4 ov = *oo;
      ov.x += en.x; ov.y += en.y; ov.z += en.z; ov.w += en.w;
      *oo = ov;
    }
  }
}

extern "C" void kernel_launch(void* const* d_in, const int* in_sizes, int n_in,
                              void* d_out, int out_size, void* d_ws, size_t ws_size,
                              hipStream_t stream) {
  const float* ent    = (const float*)d_in[0];
  const float* weight = (const float*)d_in[1];
  const float* Wq     = (const float*)d_in[2];
  const float* Wk     = (const float*)d_in[3];
  const float* Wv     = (const float*)d_in[4];
  const int*   eidx   = (const int*)d_in[5];
  const int*   etype  = (const int*)d_in[6];
  int N = in_sizes[0] / 64;
  int E = in_sizes[6];
  const int* head = eidx;
  const int* tail = eidx + E;

  // workspace layout (float units)
  float* ws    = (float*)d_ws;
  size_t o = 0;
  float* e16A  = ws + o; o += (size_t)N * 32;     // fp16 emb (N*64 halves)
  float* e16B  = ws + o; o += (size_t)N * 32;
  float* kgbuf = ws + o; o += (size_t)N * 64;     // f32 kg
  float* Gbuf  = ws + o; o += (size_t)N * 128;    // fp16 G (N*256 halves); reused as D (N*32 f32)
  float* Mf    = ws + o; o += 64 * 256;
  float* w16   = ws + o; o += 1024;               // fp16 weight (32*64 halves)
  int* epk     = (int*)(ws + o); o += (size_t)E;
  int* rowptr  = (int*)(ws + o); o += N + 1;
  int* deg     = (int*)(ws + o); o += N;
  int* cur     = (int*)(ws + o); o += N;
  int* bsum    = (int*)(ws + o); o += 512;
  int* boff    = (int*)(ws + o); o += 512;
  float* Dbuf  = Gbuf;

  int n4  = N * 64 / 4;
  int bl4 = (n4 + BD - 1) / BD;
  int ebl = (E + BD - 1) / BD;
  int sbl = (N + BD - 1) / BD;

  k_init<<<bl4, BD, 0, stream>>>((const float4*)ent, (uint2*)e16A, (float4*)d_out,
                                 n4, deg, N);
  k_deg    <<<ebl, BD, 0, stream>>>(head, deg, E);
  k_scan_a <<<sbl, BD, 0, stream>>>(deg, rowptr, bsum, N);
  k_scan_b <<<1, 512, 0, stream>>>(bsum, boff, sbl);
  k_scan_c <<<sbl, BD, 0, stream>>>(rowptr, cur, boff, N, E);
  k_scatter<<<ebl, BD, 0, stream>>>(head, tail, etype, cur, epk, E);

  float* emb = e16A;
  float* alt = e16B;
  for (int l = 0; l < 2; l++) {
    const float* wq = Wq + (size_t)l * 64 * 64;
    const float* wk = Wk + (size_t)l * 64 * 64;
    const float* wv = Wv + (size_t)l * 64 * 64;

    k_m<<<64, BD, 0, stream>>>(wq, wk, weight, Mf, (__half*)w16);
    k_g<<<(N + 63) / 64, BD, 0, stream>>>((const __half*)emb, Mf, (uint2*)Gbuf, N);
    k_fused<<<PBLK, BD, 0, stream>>>((const uint2*)emb, (const uint2*)w16,
                                     (const uint4*)Gbuf, wv, epk, rowptr, kgbuf, N);
    k_d<<<(N + 63) / 64, BD, 0, stream>>>((const float4*)kgbuf, weight, Dbuf, N);
    k_aggnorm<<<PBLK, BD, 0, stream>>>((const uint2*)emb, Dbuf, epk, rowptr,
                                       (uint2*)alt, (float*)d_out, N);
    float* tmp = emb; emb = alt; alt = tmp;
  }
}